// Round 4
// baseline (109.156 us; speedup 1.0000x reference)
//
#include <hip/hip_runtime.h>
#include <stdint.h>

// Problem constants (match reference)
#define B_ 4096
#define C_ 200
#define P_ 32
#define F_ 512
#define N_ (C_*P_)        // 6400 prototypes total
#define ALPHA_ 5.0
#define EPS_ 1e-8

typedef unsigned char u8;
typedef __attribute__((ext_vector_type(4))) float floatx4;  // MFMA C/D frag

union frag16 { int4 v; long l[2]; };   // 16 fp8 = two MFMA k-slices (virtual-K)

// ---------- prep: fp32 -> fp8 e4m3 packed + row sum-of-squares (x2 | p2) ----------
// Block = 512 threads = 8 waves = kc 0..7 of ONE 16-row group (tm). Per-wave partial
// sumsq (q-folds via shfl) -> LDS [8][16] -> wave-0 combine + plain store. No atomics,
// no zero_kernel. 656 blocks.
__global__ __launch_bounds__(512)
void prep_kernel(const float* __restrict__ outputs, const float* __restrict__ clusters,
                 u8* __restrict__ At, u8* __restrict__ Bt, float* __restrict__ sumsq) {
    const int tid = threadIdx.x;
    const int blk = blockIdx.x;
    const float* src; u8* dst; int tm, rbase;
    if (blk < B_ / 16) { tm = blk;            src = outputs;  dst = At; rbase = 0;  }
    else               { tm = blk - B_ / 16;  src = clusters; dst = Bt; rbase = B_; }
    const int o  = tm * 512 + tid;           // packed 16B-unit index
    const int kc = tid >> 6, q = (tid >> 4) & 3, r = tid & 15;
    const int row = tm * 16 + r;

    const float4* s = (const float4*)(src + (size_t)row * F_ + kc * 64 + q * 16);
    float4 v0 = s[0], v1 = s[1], v2 = s[2], v3 = s[3];
    int4 w;
    w.x = __builtin_amdgcn_cvt_pk_fp8_f32(v0.x, v0.y, 0, false);
    w.x = __builtin_amdgcn_cvt_pk_fp8_f32(v0.z, v0.w, w.x, true);
    w.y = __builtin_amdgcn_cvt_pk_fp8_f32(v1.x, v1.y, 0, false);
    w.y = __builtin_amdgcn_cvt_pk_fp8_f32(v1.z, v1.w, w.y, true);
    w.z = __builtin_amdgcn_cvt_pk_fp8_f32(v2.x, v2.y, 0, false);
    w.z = __builtin_amdgcn_cvt_pk_fp8_f32(v2.z, v2.w, w.z, true);
    w.w = __builtin_amdgcn_cvt_pk_fp8_f32(v3.x, v3.y, 0, false);
    w.w = __builtin_amdgcn_cvt_pk_fp8_f32(v3.z, v3.w, w.w, true);
    *(int4*)(dst + (size_t)o * 16) = w;

    float ss = v0.x*v0.x + v0.y*v0.y + v0.z*v0.z + v0.w*v0.w
             + v1.x*v1.x + v1.y*v1.y + v1.z*v1.z + v1.w*v1.w
             + v2.x*v2.x + v2.y*v2.y + v2.z*v2.z + v2.w*v2.w
             + v3.x*v3.x + v3.y*v3.y + v3.z*v3.z + v3.w*v3.w;
    ss += __shfl_xor(ss, 16);                // fold q^1
    ss += __shfl_xor(ss, 32);                // fold q^2 -> per-row partial (this kc)
    __shared__ float red[8][16];
    if ((tid & 63) < 16) red[kc][r] = ss;
    __syncthreads();
    if (tid < 16) {
        float t = 0.f;
#pragma unroll
        for (int k = 0; k < 8; ++k) t += red[k][tid];
        sumsq[rbase + tm * 16 + tid] = t;
    }
}

// ---------- score kernel: fp8 MFMA GEMM, TRIPLE-buffer LDS, depth-2 prefetch, ----------
// counted vmcnt(4) across raw s_barrier (T4). Per stage k:
//   s_waitcnt vmcnt(4)   -> own stage-k loads done (stage-k+1's 4 stay in flight)
//   s_barrier            -> all waves' stage-k loads done; also fences stage-(k-1)
//                           reads of buf[(k+2)%3] before we overwrite it below
//   issue stage-(k+2) global_load_lds into buf[(k+2)%3]
//   ds_read buf[k%3] -> 32 MFMA
// min_d stored transposed [C][B]; bijective XCD rectangle swizzle (8 x 25x8 rects).
#define BM 128
#define BN 128

typedef const __attribute__((address_space(1))) unsigned int gu32_t;
typedef __attribute__((address_space(3))) unsigned int lu32_t;

__device__ __forceinline__ void gld16(const u8* g, u8* l) {
    __builtin_amdgcn_global_load_lds((gu32_t*)g, (lu32_t*)l, 16, 0, 0);
}

__global__ __launch_bounds__(256, 3)
void score_kernel(const u8* __restrict__ At, const u8* __restrict__ Bt,
                  const float* __restrict__ p2, float* __restrict__ min_d) {
    __shared__ __align__(16) u8 lds[3][16384];   // [buf][ A: 8 tiles x 1KB | B: 8 tiles x 1KB ]

    const int tid  = threadIdx.x;
    const int lane = tid & 63;
    const int w    = tid >> 6;          // wave 0..3 (2x2 wave grid, 64x64 per wave)
    const int wm   = w >> 1, wn = w & 1;

    // XCD rectangle swizzle: bid%8 = XCD (round-robin dispatch); each XCD owns a 25x8 rect.
    const int bid  = blockIdx.y * 50 + blockIdx.x;
    const int xcd  = bid & 7;
    const int rr   = bid >> 3;          // 0..199 within XCD
    const int bx   = (xcd & 1) * 25 + (rr % 25);   // n-tile 0..49
    const int by   = (xcd >> 1) * 8 + (rr / 25);   // m-tile 0..31

    const int m0   = by * BM;
    const int mrow = lane & 15;
    const int quad = lane >> 4;
    const int l16  = lane * 16;

    const u8* ag = At + ((size_t)(by * 8) << 13);   // 8 row-tiles x 8KB each
    const u8* bg = Bt + ((size_t)(bx * 8) << 13);

    floatx4 zf = {0.f, 0.f, 0.f, 0.f};
    floatx4 acc[4][4];
#pragma unroll
    for (int i = 0; i < 4; ++i)
#pragma unroll
        for (int j = 0; j < 4; ++j) acc[i][j] = zf;

#define ISSUE(s, b)                                                              \
    do {                                                                         \
        gld16(ag + ((w * 8 + (s)) << 10) + l16,        lds[b] + w * 1024);       \
        gld16(ag + (((w + 4) * 8 + (s)) << 10) + l16,  lds[b] + (w + 4) * 1024); \
        gld16(bg + ((w * 8 + (s)) << 10) + l16,        lds[b] + 8192 + w * 1024);\
        gld16(bg + (((w + 4) * 8 + (s)) << 10) + l16,  lds[b] + 8192 + (w + 4) * 1024); \
    } while (0)

    // prologue: prefetch stages 0 and 1
    ISSUE(0, 0);
    ISSUE(1, 1);

#pragma unroll
    for (int kc = 0; kc < 8; ++kc) {
        if (kc < 7) asm volatile("s_waitcnt vmcnt(4)" ::: "memory");
        else        asm volatile("s_waitcnt vmcnt(0)" ::: "memory");
        __builtin_amdgcn_s_barrier();
        if (kc < 6) ISSUE(kc + 2, (kc + 2) % 3);

        const u8* L = lds[kc % 3];
        frag16 a[4], b[4];
#pragma unroll
        for (int t = 0; t < 4; ++t) {
            a[t].v = *(const int4*)(L + (wm * 4 + t) * 1024 + l16);
            b[t].v = *(const int4*)(L + 8192 + (wn * 4 + t) * 1024 + l16);
        }
#pragma unroll
        for (int s = 0; s < 2; ++s)
#pragma unroll
            for (int mt = 0; mt < 4; ++mt)
#pragma unroll
                for (int nt = 0; nt < 4; ++nt)
                    acc[mt][nt] = __builtin_amdgcn_mfma_f32_16x16x32_fp8_fp8(
                        a[mt].l[s], b[nt].l[s], acc[mt][nt], 0, 0, 0);
    }
#undef ISSUE

    // Epilogue: score = p2[n] - 2*xp; per-class min over 32 prototypes.
    // C/D layout: col = lane&15, row = quad*4 + reg.  Stores TRANSPOSED: min_d[cls*B + row].
    float pg[4];
#pragma unroll
    for (int nt = 0; nt < 4; ++nt) pg[nt] = p2[bx * BN + wn * 64 + nt * 16 + mrow];

#pragma unroll
    for (int ch = 0; ch < 2; ++ch) {
        const int cls = bx * 4 + wn * 2 + ch;
#pragma unroll
        for (int mt = 0; mt < 4; ++mt)
#pragma unroll
            for (int reg = 0; reg < 4; ++reg) {
                float v = fminf(pg[ch * 2]     - 2.0f * acc[mt][ch * 2][reg],
                                pg[ch * 2 + 1] - 2.0f * acc[mt][ch * 2 + 1][reg]);
#pragma unroll
                for (int m = 8; m >= 1; m >>= 1) v = fminf(v, __shfl_xor(v, m));
                if (mrow == 0) {
                    int grow = m0 + wm * 64 + mt * 16 + quad * 4 + reg;
                    min_d[(size_t)cls * B_ + grow] = v;   // [C][B]: 4 lanes span one 64B sector
                }
            }
    }
}

// ---------- per-sample select: [C][B] layout, class-parallel ----------
// Block = 256 threads = 16 samples x 16 class-slices; 256 blocks. Proven 3.5us.
__global__ __launch_bounds__(256)
void select_kernel(const float* __restrict__ min_d, const float* __restrict__ x2,
                   const int* __restrict__ tgt,
                   float* __restrict__ stw, float* __restrict__ sww) {
    const int sb = threadIdx.x & 15;        // sample within block
    const int sl = threadIdx.x >> 4;        // class-slice 0..15
    const int b  = blockIdx.x * 16 + sb;
    const int tc = tgt[b];

    float bw = 3.4e38f, vt = 3.4e38f;
    for (int c = sl; c < C_; c += 16) {
        float v = min_d[(size_t)c * B_ + b];
        if (c == tc) vt = v;
        else         bw = fminf(bw, v);
    }
    // fold slices sl^1 (lane^16) and sl^2 (lane^32): same sb, different slice
    bw = fminf(bw, __shfl_xor(bw, 16));
    bw = fminf(bw, __shfl_xor(bw, 32));
    vt = fminf(vt, __shfl_xor(vt, 16));
    vt = fminf(vt, __shfl_xor(vt, 32));

    __shared__ float rbw[4][16], rvt[4][16];
    const int w = threadIdx.x >> 6;
    if ((threadIdx.x & 63) < 16) { rbw[w][sb] = bw; rvt[w][sb] = vt; }
    __syncthreads();
    if (threadIdx.x < 16) {
        float fb = fminf(fminf(rbw[0][sb], rbw[1][sb]), fminf(rbw[2][sb], rbw[3][sb]));
        float fv = fminf(fminf(rvt[0][sb], rvt[1][sb]), fminf(rvt[2][sb], rvt[3][sb]));
        float xx = x2[b];
        stw[b] = xx + fv;        // = ||x - p_target*||^2 (fp8-dot approx)
        sww[b] = xx + fb;        // = ||x - p_wrong*||^2
    }
}

// Single-block reduction of 2x4096 floats + final loss
__global__ __launch_bounds__(1024)
void finalize_kernel(const float* __restrict__ stw, const float* __restrict__ sww,
                     float* __restrict__ out) {
    __shared__ float r1[16], r2[16];
    int tid = threadIdx.x;
    float s1 = 0.f, s2 = 0.f;
#pragma unroll
    for (int i = 0; i < 4; ++i) {
        s1 += stw[tid + i * 1024];
        s2 += sww[tid + i * 1024];
    }
#pragma unroll
    for (int m = 32; m >= 1; m >>= 1) { s1 += __shfl_xor(s1, m); s2 += __shfl_xor(s2, m); }
    if ((tid & 63) == 0) { r1[tid >> 6] = s1; r2[tid >> 6] = s2; }
    __syncthreads();
    if (tid == 0) {
        double t1 = 0.0, t2 = 0.0;
#pragma unroll
        for (int i = 0; i < 16; ++i) { t1 += (double)r1[i]; t2 += (double)r2[i]; }
        double denom = (double)B_ * (double)F_;
        double tl  = t1 / denom;
        double ntl = t2 / denom;
        out[0] = (float)((1.0 - ALPHA_) * tl + ALPHA_ / (ntl + EPS_));
    }
}

// ---------- launch ----------
extern "C" void kernel_launch(void* const* d_in, const int* in_sizes, int n_in,
                              void* d_out, int out_size, void* d_ws, size_t ws_size,
                              hipStream_t stream) {
    const float* outputs  = (const float*)d_in[0];
    const float* clusters = (const float*)d_in[1];
    const int*   tgt      = (const int*)d_in[2];
    float* out = (float*)d_out;

    char* ws = (char*)d_ws;
    // workspace layout (16B-aligned), total 8,692,736 bytes
    u8*     At      = (u8*)(ws);                     // packed A: 2,097,152
    u8*     Bt      = (u8*)(ws + 2097152);           // packed B: 3,276,800
    float*  sumsq   = (float*)(ws + 5373952);        // 10496*4 = 41,984 (x2 | p2)
    float*  min_d   = (float*)(ws + 5415936);        // [C][B] 200*4096*4 = 3,276,800
    float*  x2      = sumsq;
    float*  p2      = sumsq + B_;
    // per-sample partials: reuse the At region (dead after score_kernel)
    float*  stw     = (float*)(ws);                  // 4096*4
    float*  sww     = (float*)(ws + 16384);          // 4096*4

    prep_kernel<<<B_ / 16 + N_ / 16, 512, 0, stream>>>(outputs, clusters, At, Bt, sumsq); // 656
    score_kernel<<<dim3(N_ / BN, B_ / BM), 256, 0, stream>>>(At, Bt, p2, min_d);          // 50x32
    select_kernel<<<B_ / 16, 256, 0, stream>>>(min_d, x2, tgt, stw, sww);                 // 256
    finalize_kernel<<<1, 1024, 0, stream>>>(stw, sww, out);
}

// Round 5
// 108.184 us; speedup vs baseline: 1.0090x; 1.0090x over previous
//
#include <hip/hip_runtime.h>
#include <stdint.h>

// Problem constants (match reference)
#define B_ 4096
#define C_ 200
#define P_ 32
#define F_ 512
#define N_ (C_*P_)        // 6400 prototypes total
#define ALPHA_ 5.0
#define EPS_ 1e-8

typedef unsigned char u8;
typedef __attribute__((ext_vector_type(4))) float floatx4;  // MFMA C/D frag

union frag16 { int4 v; long l[2]; };   // 16 fp8 = two MFMA k-slices (virtual-K)

// ---------- prep: fp32 -> fp8 e4m3 packed + row sum-of-squares (x2 | p2) ----------
// Block = 512 threads = 8 waves = kc 0..7 of ONE 16-row group (tm). Per-wave partial
// sumsq (q-folds via shfl) -> LDS [8][16] -> wave-0 combine + plain store. 656 blocks.
__global__ __launch_bounds__(512)
void prep_kernel(const float* __restrict__ outputs, const float* __restrict__ clusters,
                 u8* __restrict__ At, u8* __restrict__ Bt, float* __restrict__ sumsq) {
    const int tid = threadIdx.x;
    const int blk = blockIdx.x;
    const float* src; u8* dst; int tm, rbase;
    if (blk < B_ / 16) { tm = blk;            src = outputs;  dst = At; rbase = 0;  }
    else               { tm = blk - B_ / 16;  src = clusters; dst = Bt; rbase = B_; }
    const int o  = tm * 512 + tid;           // packed 16B-unit index
    const int kc = tid >> 6, q = (tid >> 4) & 3, r = tid & 15;
    const int row = tm * 16 + r;

    const float4* s = (const float4*)(src + (size_t)row * F_ + kc * 64 + q * 16);
    float4 v0 = s[0], v1 = s[1], v2 = s[2], v3 = s[3];
    int4 w;
    w.x = __builtin_amdgcn_cvt_pk_fp8_f32(v0.x, v0.y, 0, false);
    w.x = __builtin_amdgcn_cvt_pk_fp8_f32(v0.z, v0.w, w.x, true);
    w.y = __builtin_amdgcn_cvt_pk_fp8_f32(v1.x, v1.y, 0, false);
    w.y = __builtin_amdgcn_cvt_pk_fp8_f32(v1.z, v1.w, w.y, true);
    w.z = __builtin_amdgcn_cvt_pk_fp8_f32(v2.x, v2.y, 0, false);
    w.z = __builtin_amdgcn_cvt_pk_fp8_f32(v2.z, v2.w, w.z, true);
    w.w = __builtin_amdgcn_cvt_pk_fp8_f32(v3.x, v3.y, 0, false);
    w.w = __builtin_amdgcn_cvt_pk_fp8_f32(v3.z, v3.w, w.w, true);
    *(int4*)(dst + (size_t)o * 16) = w;

    float ss = v0.x*v0.x + v0.y*v0.y + v0.z*v0.z + v0.w*v0.w
             + v1.x*v1.x + v1.y*v1.y + v1.z*v1.z + v1.w*v1.w
             + v2.x*v2.x + v2.y*v2.y + v2.z*v2.z + v2.w*v2.w
             + v3.x*v3.x + v3.y*v3.y + v3.z*v3.z + v3.w*v3.w;
    ss += __shfl_xor(ss, 16);                // fold q^1
    ss += __shfl_xor(ss, 32);                // fold q^2 -> per-row partial (this kc)
    __shared__ float red[8][16];
    if ((tid & 63) < 16) red[kc][r] = ss;
    __syncthreads();
    if (tid < 16) {
        float t = 0.f;
#pragma unroll
        for (int k = 0; k < 8; ++k) t += red[k][tid];
        sumsq[rbase + tm * 16 + tid] = t;
    }
}

// ---------- score kernel: 256x256 tile, 16 waves, fp8 MFMA, triple-buffer + vmcnt(2) ----
// Staged-bytes cut: 1600x128KB (200 MB) -> 400x256KB (103 MB). Wave tile stays 64x64
// (same per-wave VGPR structure as the proven 128^2 kernel). Per stage each wave issues
// only 2 global_load_lds; counted vmcnt keeps next stage's loads in flight across the
// barrier. min_d stored transposed [C][B]; bijective XCD swizzle (8 x 25x2 rects).
#define BM 256
#define BN 256

typedef const __attribute__((address_space(1))) unsigned int gu32_t;
typedef __attribute__((address_space(3))) unsigned int lu32_t;

__device__ __forceinline__ void gld16(const u8* g, u8* l) {
    __builtin_amdgcn_global_load_lds((gu32_t*)g, (lu32_t*)l, 16, 0, 0);
}

__global__ __launch_bounds__(1024)
void score_kernel(const u8* __restrict__ At, const u8* __restrict__ Bt,
                  const float* __restrict__ p2, float* __restrict__ min_d) {
    __shared__ __align__(16) u8 lds[3][32768];   // [buf][ A: 16x1KB | B: 16x1KB ]

    const int tid  = threadIdx.x;
    const int lane = tid & 63;
    const int w    = tid >> 6;          // wave 0..15 (4x4 wave grid, 64x64 per wave)
    const int wm   = w >> 2, wn = w & 3;

    // XCD swizzle: bid%8 = XCD (round-robin dispatch); each XCD owns a 25x2 rect.
    const int bid  = blockIdx.y * 25 + blockIdx.x;   // grid (25, 16) -> 400 blocks
    const int xcd  = bid & 7;
    const int rr   = bid >> 3;          // 0..49 within XCD
    const int bx   = rr % 25;           // n-tile 0..24
    const int by   = xcd * 2 + rr / 25; // m-tile 0..15

    const int mrow = lane & 15;
    const int quad = lane >> 4;
    const int l16  = lane * 16;

    const u8* ag = At + ((size_t)(by * 16) << 13);   // 16 row-tiles x 8KB each
    const u8* bg = Bt + ((size_t)(bx * 16) << 13);

    floatx4 zf = {0.f, 0.f, 0.f, 0.f};
    floatx4 acc[4][4];
#pragma unroll
    for (int i = 0; i < 4; ++i)
#pragma unroll
        for (int j = 0; j < 4; ++j) acc[i][j] = zf;

    // Wave w stages A row-tile w and B col-tile w, chunk s, into buf b.
#define ISSUE(s, b)                                                        \
    do {                                                                   \
        gld16(ag + ((w * 8 + (s)) << 10) + l16, lds[b] + w * 1024);        \
        gld16(bg + ((w * 8 + (s)) << 10) + l16, lds[b] + 16384 + w * 1024);\
    } while (0)

    // prologue: prefetch stages 0 and 1
    ISSUE(0, 0);
    ISSUE(1, 1);

#pragma unroll
    for (int kc = 0; kc < 8; ++kc) {
        if (kc < 7) asm volatile("s_waitcnt vmcnt(2)" ::: "memory");
        else        asm volatile("s_waitcnt vmcnt(0)" ::: "memory");
        __builtin_amdgcn_s_barrier();
        if (kc < 6) ISSUE(kc + 2, (kc + 2) % 3);

        const u8* L = lds[kc % 3];
        frag16 a[4], b[4];
#pragma unroll
        for (int t = 0; t < 4; ++t) {
            a[t].v = *(const int4*)(L + (wm * 4 + t) * 1024 + l16);
            b[t].v = *(const int4*)(L + 16384 + (wn * 4 + t) * 1024 + l16);
        }
#pragma unroll
        for (int s = 0; s < 2; ++s)
#pragma unroll
            for (int mt = 0; mt < 4; ++mt)
#pragma unroll
                for (int nt = 0; nt < 4; ++nt)
                    acc[mt][nt] = __builtin_amdgcn_mfma_f32_16x16x32_fp8_fp8(
                        a[mt].l[s], b[nt].l[s], acc[mt][nt], 0, 0, 0);
    }
#undef ISSUE

    // Epilogue: score = p2[n] - 2*xp; per-class min over 32 prototypes.
    // C/D layout: col = lane&15, row = quad*4 + reg.  Stores TRANSPOSED: min_d[cls*B + row],
    // vectorized: each quad-lane packs its 4 reg-values into one float4 (16B), 4 quads = 64B.
    float pg[4];
#pragma unroll
    for (int nt = 0; nt < 4; ++nt) pg[nt] = p2[bx * BN + wn * 64 + nt * 16 + mrow];

#pragma unroll
    for (int ch = 0; ch < 2; ++ch) {
        const int cls = bx * 8 + wn * 2 + ch;
#pragma unroll
        for (int mt = 0; mt < 4; ++mt) {
            float4 vv;
#pragma unroll
            for (int reg = 0; reg < 4; ++reg) {
                float v = fminf(pg[ch * 2]     - 2.0f * acc[mt][ch * 2][reg],
                                pg[ch * 2 + 1] - 2.0f * acc[mt][ch * 2 + 1][reg]);
#pragma unroll
                for (int m = 8; m >= 1; m >>= 1) v = fminf(v, __shfl_xor(v, m));
                ((float*)&vv)[reg] = v;
            }
            if (mrow == 0) {
                int grow = by * BM + wm * 64 + mt * 16 + quad * 4;
                *(float4*)&min_d[(size_t)cls * B_ + grow] = vv;
            }
        }
    }
}

// ---------- per-sample select: [C][B] layout, class-parallel ----------
// Block = 256 threads = 16 samples x 16 class-slices; 256 blocks. Proven ~3.5us.
__global__ __launch_bounds__(256)
void select_kernel(const float* __restrict__ min_d, const float* __restrict__ x2,
                   const int* __restrict__ tgt,
                   float* __restrict__ stw, float* __restrict__ sww) {
    const int sb = threadIdx.x & 15;        // sample within block
    const int sl = threadIdx.x >> 4;        // class-slice 0..15
    const int b  = blockIdx.x * 16 + sb;
    const int tc = tgt[b];

    float bw = 3.4e38f, vt = 3.4e38f;
    for (int c = sl; c < C_; c += 16) {
        float v = min_d[(size_t)c * B_ + b];
        if (c == tc) vt = v;
        else         bw = fminf(bw, v);
    }
    // fold slices sl^1 (lane^16) and sl^2 (lane^32): same sb, different slice
    bw = fminf(bw, __shfl_xor(bw, 16));
    bw = fminf(bw, __shfl_xor(bw, 32));
    vt = fminf(vt, __shfl_xor(vt, 16));
    vt = fminf(vt, __shfl_xor(vt, 32));

    __shared__ float rbw[4][16], rvt[4][16];
    const int w = threadIdx.x >> 6;
    if ((threadIdx.x & 63) < 16) { rbw[w][sb] = bw; rvt[w][sb] = vt; }
    __syncthreads();
    if (threadIdx.x < 16) {
        float fb = fminf(fminf(rbw[0][sb], rbw[1][sb]), fminf(rbw[2][sb], rbw[3][sb]));
        float fv = fminf(fminf(rvt[0][sb], rvt[1][sb]), fminf(rvt[2][sb], rvt[3][sb]));
        float xx = x2[b];
        stw[b] = xx + fv;        // = ||x - p_target*||^2 (fp8-dot approx)
        sww[b] = xx + fb;        // = ||x - p_wrong*||^2
    }
}

// Single-block reduction of 2x4096 floats + final loss
__global__ __launch_bounds__(1024)
void finalize_kernel(const float* __restrict__ stw, const float* __restrict__ sww,
                     float* __restrict__ out) {
    __shared__ float r1[16], r2[16];
    int tid = threadIdx.x;
    float s1 = 0.f, s2 = 0.f;
#pragma unroll
    for (int i = 0; i < 4; ++i) {
        s1 += stw[tid + i * 1024];
        s2 += sww[tid + i * 1024];
    }
#pragma unroll
    for (int m = 32; m >= 1; m >>= 1) { s1 += __shfl_xor(s1, m); s2 += __shfl_xor(s2, m); }
    if ((tid & 63) == 0) { r1[tid >> 6] = s1; r2[tid >> 6] = s2; }
    __syncthreads();
    if (tid == 0) {
        double t1 = 0.0, t2 = 0.0;
#pragma unroll
        for (int i = 0; i < 16; ++i) { t1 += (double)r1[i]; t2 += (double)r2[i]; }
        double denom = (double)B_ * (double)F_;
        double tl  = t1 / denom;
        double ntl = t2 / denom;
        out[0] = (float)((1.0 - ALPHA_) * tl + ALPHA_ / (ntl + EPS_));
    }
}

// ---------- launch ----------
extern "C" void kernel_launch(void* const* d_in, const int* in_sizes, int n_in,
                              void* d_out, int out_size, void* d_ws, size_t ws_size,
                              hipStream_t stream) {
    const float* outputs  = (const float*)d_in[0];
    const float* clusters = (const float*)d_in[1];
    const int*   tgt      = (const int*)d_in[2];
    float* out = (float*)d_out;

    char* ws = (char*)d_ws;
    // workspace layout (16B-aligned), total 8,692,736 bytes
    u8*     At      = (u8*)(ws);                     // packed A: 2,097,152
    u8*     Bt      = (u8*)(ws + 2097152);           // packed B: 3,276,800
    float*  sumsq   = (float*)(ws + 5373952);        // 10496*4 = 41,984 (x2 | p2)
    float*  min_d   = (float*)(ws + 5415936);        // [C][B] 200*4096*4 = 3,276,800
    float*  x2      = sumsq;
    float*  p2      = sumsq + B_;
    // per-sample partials: reuse the At region (dead after score_kernel)
    float*  stw     = (float*)(ws);                  // 4096*4
    float*  sww     = (float*)(ws + 16384);          // 4096*4

    prep_kernel<<<B_ / 16 + N_ / 16, 512, 0, stream>>>(outputs, clusters, At, Bt, sumsq); // 656
    score_kernel<<<dim3(N_ / BN, B_ / BM), 1024, 0, stream>>>(At, Bt, p2, min_d);         // 25x16
    select_kernel<<<B_ / 16, 256, 0, stream>>>(min_d, x2, tgt, stw, sww);                 // 256
    finalize_kernel<<<1, 1024, 0, stream>>>(stw, sww, out);
}